// Round 4
// baseline (3315.322 us; speedup 1.0000x reference)
//
#include <hip/hip_runtime.h>
#include <cfloat>
#include <cmath>

// NoisyTopKRouter eval-mode: logits = x @ W^T, top-2 + softmax over top-2.
// N=131072, D=2048, E=16. Outputs (concatenated flat in d_out as float32):
//   [0 .. 2N)   topk indices (as float values; ref dtype int64)
//   [2N .. 4N)  gating weights (softmax over the two top logits)
//
// Structure: x reg-staged (coalesced 1KB global_load_dwordx4) into a padded,
// double-buffered LDS slab; one barrier per 64-float phase; loads for phase
// p+1 issued before computing phase p (latency hidden under ~512cy of FMA).
// W read per-expert from global (L1-hot), never staged.
// lane = (q = lane>>4 row-quarter, e = lane&15 expert); each lane owns 4 rows
// full-width -> accumulation order bit-identical to the round-1/3 kernels.

constexpr int D = 2048;
constexpr int E = 16;
constexpr int BLOCK = 256;          // 4 waves
constexpr int ROWS_W = 16;          // rows per wave
constexpr int RB = 64;              // rows per block
constexpr int PW = 64;              // phase width (floats)
constexpr int NP = D / PW;          // 32 phases
constexpr int PITCH = 68;           // LDS row pitch (floats): 272 B, 16B-aligned;
                                    // 4-row stride = 1088 B -> bank +16 -> 2-way (free)
constexpr int SLAB = RB * PITCH;    // 4352 floats = 17408 B per buffer

__global__ __launch_bounds__(BLOCK, 4) void router_kernel(
    const float* __restrict__ x, const float* __restrict__ W,
    float* __restrict__ out, int N) {
  __shared__ float xs[2][SLAB];     // 34816 B -> 4 blocks/CU

  const int tid  = threadIdx.x;
  const int lane = tid & 63;
  const int wid  = tid >> 6;        // 0..3
  const int e    = lane & 15;       // expert owned by this lane
  const int q    = lane >> 4;       // row-quarter within the wave
  const int waverow = blockIdx.x * RB + wid * ROWS_W;

  // --- staging mapping (per wave, its own 16 rows, 64 floats per phase):
  // instr k stages rows waverow + k*4 + q, cols [p*64 + e*4, +4)
  const float* gsrc = x + (size_t)(waverow + q) * D + e * 4;  // + k*4*D + p*64
  // LDS dest for instr k: row (wid*16 + k*4 + q), col e*4
  float* ldst = &xs[0][(wid * ROWS_W + q) * PITCH + e * 4];   // + k*4*PITCH (+buf)

  // --- compute mapping: lane reads rows wid*16 + q*4 + r, float4 k
  const float* lsrc = &xs[0][(wid * ROWS_W + q * 4) * PITCH]; // + r*PITCH + k*4 (+buf)

  const float* wbase = W + e * D;   // this lane's expert row

  float4 acc[4];
  #pragma unroll
  for (int r = 0; r < 4; ++r) acc[r] = make_float4(0.f, 0.f, 0.f, 0.f);

  float4 stg[4];
  // prologue: load + write slab for phase 0 into buffer 0
  #pragma unroll
  for (int k = 0; k < 4; ++k)
    stg[k] = *reinterpret_cast<const float4*>(gsrc + (size_t)(k * 4) * D);
  #pragma unroll
  for (int k = 0; k < 4; ++k)
    *reinterpret_cast<float4*>(ldst + k * 4 * PITCH) = stg[k];
  __syncthreads();

  for (int p = 0; p < NP; ++p) {
    const int cur = p & 1;
    // issue next phase's global loads early (consumed after the compute)
    if (p + 1 < NP) {
      const float* g = gsrc + (p + 1) * PW;
      #pragma unroll
      for (int k = 0; k < 4; ++k)
        stg[k] = *reinterpret_cast<const float4*>(g + (size_t)(k * 4) * D);
    }
    // compute phase p from buf[cur]
    const float* wp = wbase + p * PW;
    const float* ls = lsrc + cur * SLAB;
    #pragma unroll
    for (int k = 0; k < 16; ++k) {
      const float4 wv = *reinterpret_cast<const float4*>(wp + 4 * k);
      #pragma unroll
      for (int r = 0; r < 4; ++r) {
        const float4 xv = *reinterpret_cast<const float4*>(ls + r * PITCH + 4 * k);
        acc[r].x = fmaf(xv.x, wv.x, acc[r].x);
        acc[r].y = fmaf(xv.y, wv.y, acc[r].y);
        acc[r].z = fmaf(xv.z, wv.z, acc[r].z);
        acc[r].w = fmaf(xv.w, wv.w, acc[r].w);
      }
    }
    // write next slab; buffers disjoint from the one just read, and the
    // previous barrier already ordered us past everyone's reads of it.
    if (p + 1 < NP) {
      float* ld = ldst + (cur ^ 1) * SLAB;
      #pragma unroll
      for (int k = 0; k < 4; ++k)
        *reinterpret_cast<float4*>(ld + k * 4 * PITCH) = stg[k];
    }
    __syncthreads();
  }

  float s_i1 = 0.f, s_i2 = 0.f, s_g1 = 0.f, s_g2 = 0.f;

  #pragma unroll
  for (int r = 0; r < 4; ++r) {
    // pairwise horizontal sum (same order as rounds 1-3, absmax was 0.0)
    float m1 = (acc[r].x + acc[r].y) + (acc[r].z + acc[r].w);
    int   i1 = e;
    float m2 = -FLT_MAX;
    int   i2 = E;
    // top-2 butterfly across the 16 expert lanes; lowest index wins ties
    #pragma unroll
    for (int mask = 1; mask < 16; mask <<= 1) {
      const float om1 = __shfl_xor(m1, mask);
      const int   oi1 = __shfl_xor(i1, mask);
      const float om2 = __shfl_xor(m2, mask);
      const int   oi2 = __shfl_xor(i2, mask);
      const bool bwin = (om1 > m1) || (om1 == m1 && oi1 < i1);
      const float a1 = bwin ? om1 : m1; const int ai1 = bwin ? oi1 : i1;
      const float l1 = bwin ? m1 : om1; const int li1 = bwin ? i1 : oi1;
      const float a2 = bwin ? om2 : m2; const int ai2 = bwin ? oi2 : i2;
      const bool lwin = (l1 > a2) || (l1 == a2 && li1 < ai2);
      m1 = a1; i1 = ai1;
      m2 = lwin ? l1 : a2; i2 = lwin ? li1 : ai2;
    }
    if (e == r) {   // lane r keeps row (q*4+r)'s result for the store below
      const float ex  = expf(m2 - m1);        // m2 <= m1 -> ex in (0,1]
      const float inv = 1.0f / (1.0f + ex);
      s_i1 = (float)i1; s_i2 = (float)i2;
      s_g1 = inv;       s_g2 = ex * inv;
    }
  }

  if (e < 4) {
    const int row = waverow + q * 4 + e;
    float2* outi = reinterpret_cast<float2*>(out);
    outi[row] = make_float2(s_i1, s_i2);
    float2* outw = reinterpret_cast<float2*>(out + (size_t)N * 2);
    outw[row] = make_float2(s_g1, s_g2);
  }
}

extern "C" void kernel_launch(void* const* d_in, const int* in_sizes, int n_in,
                              void* d_out, int out_size, void* d_ws, size_t ws_size,
                              hipStream_t stream) {
  const float* x = (const float*)d_in[0];
  const float* W = (const float*)d_in[1];
  float* out = (float*)d_out;
  const int N = in_sizes[0] / D;   // 131072
  const int grid = (N + RB - 1) / RB;  // 2048
  router_kernel<<<grid, BLOCK, 0, stream>>>(x, W, out, N);
}

// Round 5
// 706.003 us; speedup vs baseline: 4.6959x; 4.6959x over previous
//
#include <hip/hip_runtime.h>
#include <cfloat>
#include <cmath>

// NoisyTopKRouter eval-mode: logits = x @ W^T, top-2 + softmax over top-2.
// N=131072, D=2048, E=16. Outputs (concatenated flat in d_out as float32):
//   [0 .. 2N)   topk indices (as float values; ref dtype int64)
//   [2N .. 4N)  gating weights (softmax over the two top logits)
//
// x staged global->LDS via global_load_lds (zero-VGPR staging, 1 KB/instr
// fully coalesced: 4 rows x 64 floats per instruction). LDS layout mirrors
// the staging order with a 16 B pad per k-block (KPAD=260) -> reads are
// 16-lane broadcast across 4 distinct bank-quads = conflict-free.
// Prefetch of phase p+1 issued before computing phase p; one barrier/phase.
// Slabs are wave-private (each wave stages and consumes its own 16 rows).
// W read per-lane from global (L1/L2-hot), two halves of 8 float4 to bound
// register pressure under the 128-VGPR cap of __launch_bounds__(256,2).

constexpr int D = 2048;
constexpr int E = 16;
constexpr int BLOCK = 256;          // 4 waves
constexpr int RB = 64;              // rows per block (16 per wave)
constexpr int PW = 64;              // phase width (floats of D)
constexpr int NP = D / PW;          // 32 phases
constexpr int KPAD = 260;           // 256 floats per k-block + 4 pad
constexpr int WSLAB = 4 * KPAD;     // 1040 floats per wave per buffer
constexpr int SLAB = 4 * WSLAB;     // 4160 floats per buffer (4 waves)

__global__ __launch_bounds__(BLOCK, 2) void router_kernel(
    const float* __restrict__ x, const float* __restrict__ W,
    float* __restrict__ out, int N) {
  __shared__ float xs[2][SLAB];     // 2 x 16640 B -> 4 blocks/CU

  const int tid  = threadIdx.x;
  const int lane = tid & 63;
  const int wid  = tid >> 6;        // 0..3
  const int e    = lane & 15;       // expert owned by this lane
  const int q    = lane >> 4;       // lane sub-group 0..3
  const int waverow = blockIdx.x * RB + wid * 16;

  // staging: instr k, lane l -> global row (waverow + 4k + q), col p*64 + 4e
  // LDS dest: wave-uniform base + lane*16 B = k*KPAD + (q*16 + e)*4 floats
  const float* gbase = x + (size_t)(waverow + q) * D + e * 4;
  float* lwave = &xs[0][wid * WSLAB];                 // wave-uniform
  const float* rbase = &xs[0][wid * WSLAB + q * KPAD];
  const float* wbase = W + e * D;

  float4 acc[4];
  #pragma unroll
  for (int r = 0; r < 4; ++r) acc[r] = make_float4(0.f, 0.f, 0.f, 0.f);

  // prologue: stage phase 0 into buffer 0
  #pragma unroll
  for (int k = 0; k < 4; ++k)
    __builtin_amdgcn_global_load_lds(
        (const __attribute__((address_space(1))) void*)(gbase + (size_t)(4 * k) * D),
        (__attribute__((address_space(3))) void*)(lwave + k * KPAD), 16, 0, 0);
  __syncthreads();

  for (int p = 0; p < NP; ++p) {
    const int cur = p & 1;
    // issue next phase's staging first; it flies under this phase's compute
    if (p + 1 < NP) {
      const float* g = gbase + (p + 1) * PW;
      float* ld = lwave + (cur ^ 1) * SLAB;
      #pragma unroll
      for (int k = 0; k < 4; ++k)
        __builtin_amdgcn_global_load_lds(
            (const __attribute__((address_space(1))) void*)(g + (size_t)(4 * k) * D),
            (__attribute__((address_space(3))) void*)(ld + k * KPAD), 16, 0, 0);
    }
    // compute phase p: rows waverow + q*4 + r, cols [p*64, p*64+64)
    const float* wp = wbase + p * PW;
    const float* ls = rbase + cur * SLAB;
    #pragma unroll
    for (int h = 0; h < 2; ++h) {     // two halves of 32 floats: <=32 W regs live
      float4 wv[8];
      #pragma unroll
      for (int j = 0; j < 8; ++j)
        wv[j] = *reinterpret_cast<const float4*>(wp + h * 32 + 4 * j);
      #pragma unroll
      for (int j = 0; j < 8; ++j) {
        #pragma unroll
        for (int r = 0; r < 4; ++r) {
          const float4 xv =
              *reinterpret_cast<const float4*>(ls + r * 64 + h * 32 + 4 * j);
          acc[r].x = fmaf(xv.x, wv[j].x, acc[r].x);
          acc[r].y = fmaf(xv.y, wv[j].y, acc[r].y);
          acc[r].z = fmaf(xv.z, wv[j].z, acc[r].z);
          acc[r].w = fmaf(xv.w, wv[j].w, acc[r].w);
        }
      }
    }
    __syncthreads();   // prefetch landed (drained) + all reads of ls done
  }

  float s_i1 = 0.f, s_i2 = 0.f, s_g1 = 0.f, s_g2 = 0.f;

  #pragma unroll
  for (int r = 0; r < 4; ++r) {
    // pairwise horizontal sum (same order as rounds 1-4, absmax was 0.0)
    float m1 = (acc[r].x + acc[r].y) + (acc[r].z + acc[r].w);
    int   i1 = e;
    float m2 = -FLT_MAX;
    int   i2 = E;
    // top-2 butterfly across the 16 expert lanes; lowest index wins ties
    #pragma unroll
    for (int mask = 1; mask < 16; mask <<= 1) {
      const float om1 = __shfl_xor(m1, mask);
      const int   oi1 = __shfl_xor(i1, mask);
      const float om2 = __shfl_xor(m2, mask);
      const int   oi2 = __shfl_xor(i2, mask);
      const bool bwin = (om1 > m1) || (om1 == m1 && oi1 < i1);
      const float a1 = bwin ? om1 : m1; const int ai1 = bwin ? oi1 : i1;
      const float l1 = bwin ? m1 : om1; const int li1 = bwin ? i1 : oi1;
      const float a2 = bwin ? om2 : m2; const int ai2 = bwin ? oi2 : i2;
      const bool lwin = (l1 > a2) || (l1 == a2 && li1 < ai2);
      m1 = a1; i1 = ai1;
      m2 = lwin ? l1 : a2; i2 = lwin ? li1 : ai2;
    }
    if (e == r) {   // lane r keeps row (q*4+r)'s result for the store below
      const float ex  = expf(m2 - m1);        // m2 <= m1 -> ex in (0,1]
      const float inv = 1.0f / (1.0f + ex);
      s_i1 = (float)i1; s_i2 = (float)i2;
      s_g1 = inv;       s_g2 = ex * inv;
    }
  }

  if (e < 4) {
    const int row = waverow + q * 4 + e;
    float2* outi = reinterpret_cast<float2*>(out);
    outi[row] = make_float2(s_i1, s_i2);
    float2* outw = reinterpret_cast<float2*>(out + (size_t)N * 2);
    outw[row] = make_float2(s_g1, s_g2);
  }
}

extern "C" void kernel_launch(void* const* d_in, const int* in_sizes, int n_in,
                              void* d_out, int out_size, void* d_ws, size_t ws_size,
                              hipStream_t stream) {
  const float* x = (const float*)d_in[0];
  const float* W = (const float*)d_in[1];
  float* out = (float*)d_out;
  const int N = in_sizes[0] / D;       // 131072
  const int grid = (N + RB - 1) / RB;  // 2048
  router_kernel<<<grid, BLOCK, 0, stream>>>(x, W, out, N);
}